// Round 10
// baseline (404.914 us; speedup 1.0000x reference)
//
#include <hip/hip_runtime.h>
#include <hip/hip_bf16.h>

typedef __bf16 bf16x8 __attribute__((ext_vector_type(8)));
typedef float f32x4 __attribute__((ext_vector_type(4)));
static_assert(sizeof(bf16x8) == 16, "bf16x8 must be 16B");

constexpr int S = 2048, D = 128, HQ = 32, W = 1024;
constexpr float SCALE_L2E = 0.08838834764831845f * 1.4426950408889634f;

constexpr size_t O1 = (size_t)S * HQ * D;        // attn_weights offset
constexpr size_t O2 = O1 + (size_t)HQ * S * S;   // window offset
constexpr int TILE64 = 64 * 256;                 // 16 KB (64-row K image)
constexpr int TILE32 = 32 * 256;                 // 8 KB  (32-row K / 32-col V image)

__device__ __forceinline__ void gl_lds16(const void* g, void* l) {
    __builtin_amdgcn_global_load_lds(
        (const __attribute__((address_space(1))) void*)(unsigned long long)g,
        (__attribute__((address_space(3))) void*)(unsigned int)(unsigned long long)l,
        16, 0, 0);
}
__device__ __forceinline__ void st4(float* p, f32x4 v) {
    *reinterpret_cast<f32x4*>(p) = v;
}

// ---------------- prep: K,V -> bf16 pre-swizzled tile images in ws ----------------
__global__ __launch_bounds__(256)
void prep_kernel(const float* __restrict__ K, const float* __restrict__ V,
                 char* __restrict__ KbI, char* __restrict__ VtI)
{
    __shared__ __attribute__((aligned(16))) __bf16 Vs[128][72];
    const int b = blockIdx.x, hkv = b >> 5, kt = b & 31;
    const int tid = threadIdx.x;
    const float* Ks   = K + ((size_t)hkv * S + kt * 64) * D;
    const float* Vsrc = V + ((size_t)hkv * S + kt * 64) * D;
    char* Kimg = KbI + (size_t)(hkv * 32 + kt) * TILE64;
    char* Vimg = VtI + (size_t)(hkv * 32 + kt) * TILE64;

    #pragma unroll
    for (int i = 0; i < 4; ++i) {
        int idx = tid + i * 256;
        int r = idx >> 4, sl = idx & 15;
        float4 a = *reinterpret_cast<const float4*>(Ks + r * D + sl * 8);
        float4 c = *reinterpret_cast<const float4*>(Ks + r * D + sl * 8 + 4);
        bf16x8 f = {(__bf16)a.x, (__bf16)a.y, (__bf16)a.z, (__bf16)a.w,
                    (__bf16)c.x, (__bf16)c.y, (__bf16)c.z, (__bf16)c.w};
        *reinterpret_cast<bf16x8*>(Kimg + r * 256 + ((sl * 16) ^ ((r & 7) << 4))) = f;
    }
    #pragma unroll
    for (int i = 0; i < 8; ++i) {
        int idx = tid + i * 256;
        int r = idx >> 5, c = (idx & 31) * 4;
        float4 vv = *reinterpret_cast<const float4*>(Vsrc + r * D + c);
        Vs[c + 0][r] = (__bf16)vv.x; Vs[c + 1][r] = (__bf16)vv.y;
        Vs[c + 2][r] = (__bf16)vv.z; Vs[c + 3][r] = (__bf16)vv.w;
    }
    __syncthreads();
    #pragma unroll
    for (int i = 0; i < 4; ++i) {
        int idx = tid + i * 256;            // 2 images x 512 chunks
        int img = idx >> 9;
        int rem = idx & 511;
        int d = rem >> 2, sl = rem & 3;
        bf16x8 v = *reinterpret_cast<const bf16x8*>(&Vs[d][img * 32 + sl * 8]);
        *reinterpret_cast<bf16x8*>(Vimg + img * TILE32 + d * 64 + ((sl * 16) ^ ((d & 3) << 4))) = v;
    }
}

// ------- main: 4-wave blocks, zero-fill overlapped into phase A, counted vmcnt -------
__global__ __launch_bounds__(256, 4)
void attn_fused6(const float* __restrict__ Q, const char* __restrict__ KbI,
                 const char* __restrict__ VtI, float* __restrict__ out)
{
    __shared__ __attribute__((aligned(16))) char BUF[4][TILE32];   // 32 KB
    __shared__ __attribute__((aligned(16))) char PST[4][1024];     // 4 KB -> 36 KB

    const int bid = blockIdx.x;
    const int j   = bid >> 5;
    // per-CU resident set -> qt {16+x, 15-x, 31-x, x}: balanced iteration totals
    const int qt = (j < 8) ? (16 + j) : (j < 16) ? (23 - j) : (j < 24) ? (47 - j) : (j - 24);
    const int b5 = bid & 31;
    const int h  = (b5 & 7) * 4 + (b5 >> 3);   // hkv == bid%8 == XCD id
    const int hkv = h >> 2;
    const int q0  = qt << 6;
    const int tid = threadIdx.x, wave = tid >> 6, lane = tid & 63;
    const int lo = lane & 15, hi = lane >> 4;
    const int qw0 = q0 + wave * 16;
    const bool winw = (qt >= 16);

    const char* Ktiles = KbI + (size_t)hkv * 32 * TILE64;
    const char* Vtiles = VtI + (size_t)hkv * 32 * TILE64;
    const float* Qh = Q + (size_t)h * S * D;

    // zero-fill work list (per lane): unit u -> tile tz, P or W, f4 slot j
    const int qz  = qw0 + (lane >> 2);
    const int c0z = (lane & 3) * 16;
    const size_t basePz = O1 + ((size_t)h * S + qz) * S;
    const size_t baseWz = winw ? (O2 + ((size_t)h * W + (qz - W)) * S) : 0;
    const int utot = (31 - qt) * (winw ? 8 : 4);
    const f32x4 z4 = {0.f, 0.f, 0.f, 0.f};
    auto zstore = [&](int u) {
        int tz, jslot; size_t base;
        if (winw) { tz = (qt + 1) + (u >> 3); int sub = u & 7;
                    base = (sub >> 2) ? baseWz : basePz; jslot = sub & 3; }
        else      { tz = (qt + 1) + (u >> 2); base = basePz; jslot = u & 3; }
        st4(out + base + (size_t)tz * 64 + c0z + jslot * 4, z4);
    };

    // Q fragments (pre-scaled)
    bf16x8 qf[4];
    {
        const float* qs = Qh + (size_t)(qw0 + lo) * D + hi * 8;
        #pragma unroll
        for (int dc = 0; dc < 4; ++dc) {
            float4 a = *reinterpret_cast<const float4*>(qs + dc * 32);
            float4 b = *reinterpret_cast<const float4*>(qs + dc * 32 + 4);
            bf16x8 f;
            f[0] = (__bf16)(a.x * SCALE_L2E); f[1] = (__bf16)(a.y * SCALE_L2E);
            f[2] = (__bf16)(a.z * SCALE_L2E); f[3] = (__bf16)(a.w * SCALE_L2E);
            f[4] = (__bf16)(b.x * SCALE_L2E); f[5] = (__bf16)(b.y * SCALE_L2E);
            f[6] = (__bf16)(b.z * SCALE_L2E); f[7] = (__bf16)(b.w * SCALE_L2E);
            qf[dc] = f;
        }
    }

    // ====== phase A: row sums (KVBLK=64, dbuf) + interleaved zero-fill ======
    float lsum[4] = {0.f, 0.f, 0.f, 0.f};
    int uz = 0;
    {
        #pragma unroll
        for (int i = 0; i < 4; ++i)
            gl_lds16(Ktiles + (wave * 4 + i) * 1024 + lane * 16,
                     &BUF[0][0] + (wave * 4 + i) * 1024);
        __builtin_amdgcn_sched_barrier(0);
        asm volatile("s_waitcnt vmcnt(0)" ::: "memory");
        __builtin_amdgcn_s_barrier();
        __builtin_amdgcn_sched_barrier(0);

        int cur = 0;
        for (int kt = 0; kt <= qt; ++kt) {
            if (kt < qt) {
                const char* src = Ktiles + (size_t)(kt + 1) * TILE64;
                char* dst = &BUF[(cur ^ 1) * 2][0];
                #pragma unroll
                for (int i = 0; i < 4; ++i)
                    gl_lds16(src + (wave * 4 + i) * 1024 + lane * 16, dst + (wave * 4 + i) * 1024);
                __builtin_amdgcn_sched_barrier(0);
            }
            const char* KtB = &BUF[cur * 2][0];
            #pragma unroll
            for (int cg = 0; cg < 4; ++cg) {
                f32x4 acc = {0.f, 0.f, 0.f, 0.f};
                const int row = cg * 16 + lo, swzr = (row & 7) << 4;
                #pragma unroll
                for (int dc = 0; dc < 4; ++dc) {
                    bf16x8 kf = *reinterpret_cast<const bf16x8*>(
                        KtB + row * 256 + ((hi * 16 + dc * 64) ^ swzr));
                    acc = __builtin_amdgcn_mfma_f32_16x16x32_bf16(qf[dc], kf, acc, 0, 0, 0);
                }
                const int k = (kt << 6) + cg * 16 + lo;
                #pragma unroll
                for (int r = 0; r < 4; ++r) {
                    int q = qw0 + hi * 4 + r;
                    lsum[r] += (k <= q) ? exp2f(acc[r]) : 0.f;
                }
            }
            // interleaved zero-fill: exactly 8 stores -> counted wait keeps them in flight
            if (uz + 8 <= utot) {
                #pragma unroll
                for (int zi = 0; zi < 8; ++zi) zstore(uz + zi);
                uz += 8;
                __builtin_amdgcn_sched_barrier(0);
                asm volatile("s_waitcnt vmcnt(8) lgkmcnt(0)" ::: "memory");
            } else {
                for (int zi = uz; zi < utot; ++zi) zstore(zi);
                uz = utot;
                __builtin_amdgcn_sched_barrier(0);
                asm volatile("s_waitcnt vmcnt(0) lgkmcnt(0)" ::: "memory");
            }
            __builtin_amdgcn_s_barrier();
            __builtin_amdgcn_sched_barrier(0);
            cur ^= 1;
        }
    }
    // bulk-flush remaining zeros (short-qt blocks); drained at phase-B prologue
    for (int u = uz; u < utot; ++u) zstore(u);

    float rcp_[4];
    #pragma unroll
    for (int r = 0; r < 4; ++r) {
        float v = lsum[r];
        v += __shfl_xor(v, 1); v += __shfl_xor(v, 2);
        v += __shfl_xor(v, 4); v += __shfl_xor(v, 8);
        rcp_[r] = 1.0f / v;
    }

    // ====== phase B: KVBLK=32, K db = BUF[0/1], V db = BUF[2/3], counted vmcnt ======
    f32x4 oacc[8];
    #pragma unroll
    for (int i = 0; i < 8; ++i) oacc[i] = (f32x4){0.f, 0.f, 0.f, 0.f};
    char* Ps = PST[wave];
    const int nk32 = (qt + 1) * 2;

    {
        #pragma unroll
        for (int i = 0; i < 2; ++i) {
            gl_lds16(Ktiles + (wave * 2 + i) * 1024 + lane * 16, &BUF[0][0] + (wave * 2 + i) * 1024);
            gl_lds16(Vtiles + (wave * 2 + i) * 1024 + lane * 16, &BUF[2][0] + (wave * 2 + i) * 1024);
        }
        __builtin_amdgcn_sched_barrier(0);
        asm volatile("s_waitcnt vmcnt(0)" ::: "memory");
        __builtin_amdgcn_s_barrier();
        __builtin_amdgcn_sched_barrier(0);
    }

    int cur = 0;
    for (int t = 0; t < nk32; ++t) {
        const bool more = (t + 1 < nk32);
        if (more) {
            const char* sk = Ktiles + (size_t)(t + 1) * TILE32;
            const char* sv = Vtiles + (size_t)(t + 1) * TILE32;
            char* dk = &BUF[cur ^ 1][0];
            char* dv = &BUF[2 + (cur ^ 1)][0];
            #pragma unroll
            for (int i = 0; i < 2; ++i) {
                gl_lds16(sk + (wave * 2 + i) * 1024 + lane * 16, dk + (wave * 2 + i) * 1024);
                gl_lds16(sv + (wave * 2 + i) * 1024 + lane * 16, dv + (wave * 2 + i) * 1024);
            }
            __builtin_amdgcn_sched_barrier(0);
        }
        const char* KtB = &BUF[cur][0];
        const char* VtB = &BUF[2 + cur][0];
        const int kbase = t * 32;

        // QK^T (32 k-cols) -> p -> per-wave P strip
        #pragma unroll
        for (int cg = 0; cg < 2; ++cg) {
            f32x4 acc = {0.f, 0.f, 0.f, 0.f};
            const int row = cg * 16 + lo, swzr = (row & 7) << 4;
            #pragma unroll
            for (int dc = 0; dc < 4; ++dc) {
                bf16x8 kf = *reinterpret_cast<const bf16x8*>(
                    KtB + row * 256 + ((hi * 16 + dc * 64) ^ swzr));
                acc = __builtin_amdgcn_mfma_f32_16x16x32_bf16(qf[dc], kf, acc, 0, 0, 0);
            }
            const int k = kbase + cg * 16 + lo;
            #pragma unroll
            for (int r = 0; r < 4; ++r) {
                const int q = qw0 + hi * 4 + r;
                float pv = (k <= q) ? exp2f(acc[r]) * rcp_[r] : 0.f;
                const int prow = hi * 4 + r;
                *reinterpret_cast<__bf16*>(
                    Ps + prow * 64 + ((2 * (cg * 16 + lo)) ^ ((prow & 3) << 4))) = (__bf16)pv;
            }
        }

        // P (+window) stores from strip readback
        {
            const int row = lane >> 2;
            const int sl  = lane & 3;
            const int q = qw0 + row;
            bf16x8 pv8 = *reinterpret_cast<const bf16x8*>(
                Ps + row * 64 + ((sl * 16) ^ ((row & 3) << 4)));
            f32x4 f0 = {(float)pv8[0], (float)pv8[1], (float)pv8[2], (float)pv8[3]};
            f32x4 f1 = {(float)pv8[4], (float)pv8[5], (float)pv8[6], (float)pv8[7]};
            float* dstP = out + O1 + ((size_t)h * S + q) * S + kbase + sl * 8;
            st4(dstP, f0);
            st4(dstP + 4, f1);
            if (winw) {
                float* dstW = out + O2 + ((size_t)h * W + (q - W)) * S + kbase + sl * 8;
                st4(dstW, f0);
                st4(dstW + 4, f1);
            }
        }

        // PV accumulate
        {
            bf16x8 pf = *reinterpret_cast<const bf16x8*>(
                Ps + lo * 64 + ((hi * 16) ^ ((lo & 3) << 4)));
            #pragma unroll
            for (int dg = 0; dg < 8; ++dg) {
                const int d = dg * 16 + lo;
                bf16x8 vf = *reinterpret_cast<const bf16x8*>(
                    VtB + d * 64 + ((hi * 16) ^ ((d & 3) << 4)));
                oacc[dg] = __builtin_amdgcn_mfma_f32_16x16x32_bf16(pf, vf, oacc[dg], 0, 0, 0);
            }
        }

        if (more) {
            __builtin_amdgcn_sched_barrier(0);
            if (winw) asm volatile("s_waitcnt vmcnt(4) lgkmcnt(0)" ::: "memory");
            else      asm volatile("s_waitcnt vmcnt(2) lgkmcnt(0)" ::: "memory");
            __builtin_amdgcn_s_barrier();
            __builtin_amdgcn_sched_barrier(0);
        }
        cur ^= 1;
    }

    // attn_output (S, HQ, D)
    #pragma unroll
    for (int dg = 0; dg < 8; ++dg) {
        #pragma unroll
        for (int r = 0; r < 4; ++r) {
            const int q = qw0 + hi * 4 + r;
            out[((size_t)q * HQ + h) * D + dg * 16 + lo] = oacc[dg][r];
        }
    }
}

extern "C" void kernel_launch(void* const* d_in, const int* in_sizes, int n_in,
                              void* d_out, int out_size, void* d_ws, size_t ws_size,
                              hipStream_t stream)
{
    const float* Q = (const float*)d_in[0];
    const float* K = (const float*)d_in[1];
    const float* V = (const float*)d_in[2];
    float* out = (float*)d_out;

    char* KbI = (char*)d_ws;                                   // 4 MB tile images
    char* VtI = (char*)d_ws + (size_t)4 * 1024 * 1024;         // 4 MB tile images

    hipLaunchKernelGGL(prep_kernel, dim3(256),  dim3(256), 0, stream, K, V, KbI, VtI);
    hipLaunchKernelGGL(attn_fused6, dim3(1024), dim3(256), 0, stream, Q, KbI, VtI, out);
}

// Round 11
// 306.343 us; speedup vs baseline: 1.3218x; 1.3218x over previous
//
#include <hip/hip_runtime.h>
#include <hip/hip_bf16.h>

typedef __bf16 bf16x8 __attribute__((ext_vector_type(8)));
typedef float f32x4 __attribute__((ext_vector_type(4)));
static_assert(sizeof(bf16x8) == 16, "bf16x8 must be 16B");

constexpr int S = 2048, D = 128, HQ = 32, W = 1024;
constexpr float SCALE_L2E = 0.08838834764831845f * 1.4426950408889634f;

constexpr size_t O1 = (size_t)S * HQ * D;        // attn_weights offset
constexpr size_t O2 = O1 + (size_t)HQ * S * S;   // window offset
constexpr int TILE64 = 64 * 256;                 // 16 KB (64-row K image)
constexpr int TILE32 = 32 * 256;                 // 8 KB  (32-row K / 32-col V image)

__device__ __forceinline__ void gl_lds16(const void* g, void* l) {
    __builtin_amdgcn_global_load_lds(
        (const __attribute__((address_space(1))) void*)(unsigned long long)g,
        (__attribute__((address_space(3))) void*)(unsigned int)(unsigned long long)l,
        16, 0, 0);
}
__device__ __forceinline__ void st4(float* p, f32x4 v) {
    *reinterpret_cast<f32x4*>(p) = v;
}

// ---------------- prep: K,V -> bf16 pre-swizzled tile images in ws ----------------
__global__ __launch_bounds__(256)
void prep_kernel(const float* __restrict__ K, const float* __restrict__ V,
                 char* __restrict__ KbI, char* __restrict__ VtI)
{
    __shared__ __attribute__((aligned(16))) __bf16 Vs[128][72];
    const int b = blockIdx.x, hkv = b >> 5, kt = b & 31;
    const int tid = threadIdx.x;
    const float* Ks   = K + ((size_t)hkv * S + kt * 64) * D;
    const float* Vsrc = V + ((size_t)hkv * S + kt * 64) * D;
    char* Kimg = KbI + (size_t)(hkv * 32 + kt) * TILE64;
    char* Vimg = VtI + (size_t)(hkv * 32 + kt) * TILE64;

    #pragma unroll
    for (int i = 0; i < 4; ++i) {
        int idx = tid + i * 256;
        int r = idx >> 4, sl = idx & 15;
        float4 a = *reinterpret_cast<const float4*>(Ks + r * D + sl * 8);
        float4 c = *reinterpret_cast<const float4*>(Ks + r * D + sl * 8 + 4);
        bf16x8 f = {(__bf16)a.x, (__bf16)a.y, (__bf16)a.z, (__bf16)a.w,
                    (__bf16)c.x, (__bf16)c.y, (__bf16)c.z, (__bf16)c.w};
        *reinterpret_cast<bf16x8*>(Kimg + r * 256 + ((sl * 16) ^ ((r & 7) << 4))) = f;
    }
    #pragma unroll
    for (int i = 0; i < 8; ++i) {
        int idx = tid + i * 256;
        int r = idx >> 5, c = (idx & 31) * 4;
        float4 vv = *reinterpret_cast<const float4*>(Vsrc + r * D + c);
        Vs[c + 0][r] = (__bf16)vv.x; Vs[c + 1][r] = (__bf16)vv.y;
        Vs[c + 2][r] = (__bf16)vv.z; Vs[c + 3][r] = (__bf16)vv.w;
    }
    __syncthreads();
    #pragma unroll
    for (int i = 0; i < 4; ++i) {
        int idx = tid + i * 256;            // 2 images x 512 chunks
        int img = idx >> 9;
        int rem = idx & 511;
        int d = rem >> 2, sl = rem & 3;
        bf16x8 v = *reinterpret_cast<const bf16x8*>(&Vs[d][img * 32 + sl * 8]);
        *reinterpret_cast<bf16x8*>(Vimg + img * TILE32 + d * 64 + ((sl * 16) ^ ((d & 3) << 4))) = v;
    }
}

// ---------------- lsum: phase A standalone -> rcp in ws ----------------
__global__ __launch_bounds__(256, 4)
void lsum_kernel(const float* __restrict__ Q, const char* __restrict__ KbI,
                 float* __restrict__ lsr)
{
    __shared__ __attribute__((aligned(16))) char BUF[2][TILE64];   // 32 KB

    const int bid = blockIdx.x;
    const int j   = bid >> 5;
    const int qt = (j < 8) ? (16 + j) : (j < 16) ? (23 - j) : (j < 24) ? (47 - j) : (j - 24);
    const int b5 = bid & 31;
    const int h  = (b5 & 7) * 4 + (b5 >> 3);   // hkv == bid%8 == XCD id
    const int hkv = h >> 2;
    const int tid = threadIdx.x, wave = tid >> 6, lane = tid & 63;
    const int lo = lane & 15, hi = lane >> 4;
    const int qw0 = (qt << 6) + wave * 16;

    const char* Ktiles = KbI + (size_t)hkv * 32 * TILE64;
    const float* Qh = Q + (size_t)h * S * D;

    bf16x8 qf[4];
    {
        const float* qs = Qh + (size_t)(qw0 + lo) * D + hi * 8;
        #pragma unroll
        for (int dc = 0; dc < 4; ++dc) {
            float4 a = *reinterpret_cast<const float4*>(qs + dc * 32);
            float4 b = *reinterpret_cast<const float4*>(qs + dc * 32 + 4);
            bf16x8 f;
            f[0] = (__bf16)(a.x * SCALE_L2E); f[1] = (__bf16)(a.y * SCALE_L2E);
            f[2] = (__bf16)(a.z * SCALE_L2E); f[3] = (__bf16)(a.w * SCALE_L2E);
            f[4] = (__bf16)(b.x * SCALE_L2E); f[5] = (__bf16)(b.y * SCALE_L2E);
            f[6] = (__bf16)(b.z * SCALE_L2E); f[7] = (__bf16)(b.w * SCALE_L2E);
            qf[dc] = f;
        }
    }

    float lsum[4] = {0.f, 0.f, 0.f, 0.f};
    {
        #pragma unroll
        for (int i = 0; i < 4; ++i)
            gl_lds16(Ktiles + (wave * 4 + i) * 1024 + lane * 16,
                     &BUF[0][0] + (wave * 4 + i) * 1024);
        __builtin_amdgcn_sched_barrier(0);
        asm volatile("s_waitcnt vmcnt(0)" ::: "memory");
        __builtin_amdgcn_s_barrier();
        __builtin_amdgcn_sched_barrier(0);

        int cur = 0;
        for (int kt = 0; kt <= qt; ++kt) {
            if (kt < qt) {
                const char* src = Ktiles + (size_t)(kt + 1) * TILE64;
                char* dst = &BUF[cur ^ 1][0];
                #pragma unroll
                for (int i = 0; i < 4; ++i)
                    gl_lds16(src + (wave * 4 + i) * 1024 + lane * 16, dst + (wave * 4 + i) * 1024);
                __builtin_amdgcn_sched_barrier(0);
            }
            const char* KtB = &BUF[cur][0];
            #pragma unroll
            for (int cg = 0; cg < 4; ++cg) {
                f32x4 acc = {0.f, 0.f, 0.f, 0.f};
                const int row = cg * 16 + lo, swzr = (row & 7) << 4;
                #pragma unroll
                for (int dc = 0; dc < 4; ++dc) {
                    bf16x8 kf = *reinterpret_cast<const bf16x8*>(
                        KtB + row * 256 + ((hi * 16 + dc * 64) ^ swzr));
                    acc = __builtin_amdgcn_mfma_f32_16x16x32_bf16(qf[dc], kf, acc, 0, 0, 0);
                }
                const int k = (kt << 6) + cg * 16 + lo;
                #pragma unroll
                for (int r = 0; r < 4; ++r) {
                    int q = qw0 + hi * 4 + r;
                    lsum[r] += (k <= q) ? exp2f(acc[r]) : 0.f;
                }
            }
            __builtin_amdgcn_sched_barrier(0);
            asm volatile("s_waitcnt vmcnt(0) lgkmcnt(0)" ::: "memory");
            __builtin_amdgcn_s_barrier();
            __builtin_amdgcn_sched_barrier(0);
            cur ^= 1;
        }
    }
    #pragma unroll
    for (int r = 0; r < 4; ++r) {
        float v = lsum[r];
        v += __shfl_xor(v, 1); v += __shfl_xor(v, 2);
        v += __shfl_xor(v, 4); v += __shfl_xor(v, 8);
        if (lo == 0) lsr[h * S + qw0 + hi * 4 + r] = 1.0f / v;
    }
}

// ---------------- main: phase B standalone (stores from iteration 0) ----------------
__global__ __launch_bounds__(256, 4)
void attn_main(const float* __restrict__ Q, const char* __restrict__ KbI,
               const char* __restrict__ VtI, const float* __restrict__ lsr,
               float* __restrict__ out)
{
    __shared__ __attribute__((aligned(16))) char BUF[4][TILE32];   // 32 KB
    __shared__ __attribute__((aligned(16))) char PST[4][1024];     // 4 KB -> 36 KB

    const int bid = blockIdx.x;
    const int j   = bid >> 5;
    const int qt = (j < 8) ? (16 + j) : (j < 16) ? (23 - j) : (j < 24) ? (47 - j) : (j - 24);
    const int b5 = bid & 31;
    const int h  = (b5 & 7) * 4 + (b5 >> 3);
    const int hkv = h >> 2;
    const int q0  = qt << 6;
    const int tid = threadIdx.x, wave = tid >> 6, lane = tid & 63;
    const int lo = lane & 15, hi = lane >> 4;
    const int qw0 = q0 + wave * 16;
    const bool winw = (qt >= 16);

    const char* Ktiles = KbI + (size_t)hkv * 32 * TILE64;
    const char* Vtiles = VtI + (size_t)hkv * 32 * TILE64;
    const float* Qh = Q + (size_t)h * S * D;

    bf16x8 qf[4];
    {
        const float* qs = Qh + (size_t)(qw0 + lo) * D + hi * 8;
        #pragma unroll
        for (int dc = 0; dc < 4; ++dc) {
            float4 a = *reinterpret_cast<const float4*>(qs + dc * 32);
            float4 b = *reinterpret_cast<const float4*>(qs + dc * 32 + 4);
            bf16x8 f;
            f[0] = (__bf16)(a.x * SCALE_L2E); f[1] = (__bf16)(a.y * SCALE_L2E);
            f[2] = (__bf16)(a.z * SCALE_L2E); f[3] = (__bf16)(a.w * SCALE_L2E);
            f[4] = (__bf16)(b.x * SCALE_L2E); f[5] = (__bf16)(b.y * SCALE_L2E);
            f[6] = (__bf16)(b.z * SCALE_L2E); f[7] = (__bf16)(b.w * SCALE_L2E);
            qf[dc] = f;
        }
    }
    float rcp_[4];
    {
        float4 rc = *reinterpret_cast<const float4*>(lsr + h * S + qw0 + hi * 4);
        rcp_[0] = rc.x; rcp_[1] = rc.y; rcp_[2] = rc.z; rcp_[3] = rc.w;
    }

    f32x4 oacc[8];
    #pragma unroll
    for (int i = 0; i < 8; ++i) oacc[i] = (f32x4){0.f, 0.f, 0.f, 0.f};
    char* Ps = PST[wave];
    const int nk32 = (qt + 1) * 2;

    {
        #pragma unroll
        for (int i = 0; i < 2; ++i) {
            gl_lds16(Ktiles + (wave * 2 + i) * 1024 + lane * 16, &BUF[0][0] + (wave * 2 + i) * 1024);
            gl_lds16(Vtiles + (wave * 2 + i) * 1024 + lane * 16, &BUF[2][0] + (wave * 2 + i) * 1024);
        }
        __builtin_amdgcn_sched_barrier(0);
        asm volatile("s_waitcnt vmcnt(0)" ::: "memory");
        __builtin_amdgcn_s_barrier();
        __builtin_amdgcn_sched_barrier(0);
    }

    int cur = 0;
    for (int t = 0; t < nk32; ++t) {
        const bool more = (t + 1 < nk32);
        if (more) {
            const char* sk = Ktiles + (size_t)(t + 1) * TILE32;
            const char* sv = Vtiles + (size_t)(t + 1) * TILE32;
            char* dk = &BUF[cur ^ 1][0];
            char* dv = &BUF[2 + (cur ^ 1)][0];
            #pragma unroll
            for (int i = 0; i < 2; ++i) {
                gl_lds16(sk + (wave * 2 + i) * 1024 + lane * 16, dk + (wave * 2 + i) * 1024);
                gl_lds16(sv + (wave * 2 + i) * 1024 + lane * 16, dv + (wave * 2 + i) * 1024);
            }
            __builtin_amdgcn_sched_barrier(0);
        }
        const char* KtB = &BUF[cur][0];
        const char* VtB = &BUF[2 + cur][0];
        const int kbase = t * 32;

        #pragma unroll
        for (int cg = 0; cg < 2; ++cg) {
            f32x4 acc = {0.f, 0.f, 0.f, 0.f};
            const int row = cg * 16 + lo, swzr = (row & 7) << 4;
            #pragma unroll
            for (int dc = 0; dc < 4; ++dc) {
                bf16x8 kf = *reinterpret_cast<const bf16x8*>(
                    KtB + row * 256 + ((hi * 16 + dc * 64) ^ swzr));
                acc = __builtin_amdgcn_mfma_f32_16x16x32_bf16(qf[dc], kf, acc, 0, 0, 0);
            }
            const int k = kbase + cg * 16 + lo;
            #pragma unroll
            for (int r = 0; r < 4; ++r) {
                const int q = qw0 + hi * 4 + r;
                float pv = (k <= q) ? exp2f(acc[r]) * rcp_[r] : 0.f;
                const int prow = hi * 4 + r;
                *reinterpret_cast<__bf16*>(
                    Ps + prow * 64 + ((2 * (cg * 16 + lo)) ^ ((prow & 3) << 4))) = (__bf16)pv;
            }
        }

        {
            const int row = lane >> 2;
            const int sl  = lane & 3;
            const int q = qw0 + row;
            bf16x8 pv8 = *reinterpret_cast<const bf16x8*>(
                Ps + row * 64 + ((sl * 16) ^ ((row & 3) << 4)));
            f32x4 f0 = {(float)pv8[0], (float)pv8[1], (float)pv8[2], (float)pv8[3]};
            f32x4 f1 = {(float)pv8[4], (float)pv8[5], (float)pv8[6], (float)pv8[7]};
            float* dstP = out + O1 + ((size_t)h * S + q) * S + kbase + sl * 8;
            st4(dstP, f0);
            st4(dstP + 4, f1);
            if (winw) {
                float* dstW = out + O2 + ((size_t)h * W + (q - W)) * S + kbase + sl * 8;
                st4(dstW, f0);
                st4(dstW + 4, f1);
            }
        }

        {
            bf16x8 pf = *reinterpret_cast<const bf16x8*>(
                Ps + lo * 64 + ((hi * 16) ^ ((lo & 3) << 4)));
            #pragma unroll
            for (int dg = 0; dg < 8; ++dg) {
                const int d = dg * 16 + lo;
                bf16x8 vf = *reinterpret_cast<const bf16x8*>(
                    VtB + d * 64 + ((hi * 16) ^ ((d & 3) << 4)));
                oacc[dg] = __builtin_amdgcn_mfma_f32_16x16x32_bf16(pf, vf, oacc[dg], 0, 0, 0);
            }
        }

        if (more) {
            __builtin_amdgcn_sched_barrier(0);
            if (winw) asm volatile("s_waitcnt vmcnt(4) lgkmcnt(0)" ::: "memory");
            else      asm volatile("s_waitcnt vmcnt(2) lgkmcnt(0)" ::: "memory");
            __builtin_amdgcn_s_barrier();
            __builtin_amdgcn_sched_barrier(0);
        }
        cur ^= 1;
    }

    // zero-fill masked tiles (coalesced 64B per lane)
    {
        const int zr = lane >> 2;
        const int c0 = (lane & 3) * 16;
        const f32x4 z = {0.f, 0.f, 0.f, 0.f};
        const int q = qw0 + zr;
        for (int kt = qt + 1; kt < 32; ++kt) {
            float* dp = out + O1 + ((size_t)h * S + q) * S + kt * 64 + c0;
            #pragma unroll
            for (int jj = 0; jj < 4; ++jj) st4(dp + jj * 4, z);
            if (winw) {
                float* dw = out + O2 + ((size_t)h * W + (q - W)) * S + kt * 64 + c0;
                #pragma unroll
                for (int jj = 0; jj < 4; ++jj) st4(dw + jj * 4, z);
            }
        }
    }

    // attn_output (S, HQ, D)
    #pragma unroll
    for (int dg = 0; dg < 8; ++dg) {
        #pragma unroll
        for (int r = 0; r < 4; ++r) {
            const int q = qw0 + hi * 4 + r;
            out[((size_t)q * HQ + h) * D + dg * 16 + lo] = oacc[dg][r];
        }
    }
}

extern "C" void kernel_launch(void* const* d_in, const int* in_sizes, int n_in,
                              void* d_out, int out_size, void* d_ws, size_t ws_size,
                              hipStream_t stream)
{
    const float* Q = (const float*)d_in[0];
    const float* K = (const float*)d_in[1];
    const float* V = (const float*)d_in[2];
    float* out = (float*)d_out;

    char*  KbI = (char*)d_ws;                                    // 4 MB tile images
    char*  VtI = (char*)d_ws + (size_t)4 * 1024 * 1024;          // 4 MB tile images
    float* lsr = (float*)((char*)d_ws + (size_t)8 * 1024 * 1024);// 256 KB rcp

    hipLaunchKernelGGL(prep_kernel, dim3(256),  dim3(256), 0, stream, K, V, KbI, VtI);
    hipLaunchKernelGGL(lsum_kernel, dim3(1024), dim3(256), 0, stream, Q, KbI, lsr);
    hipLaunchKernelGGL(attn_main,   dim3(1024), dim3(256), 0, stream, Q, KbI, VtI, lsr, out);
}